// Round 2
// baseline (398.615 us; speedup 1.0000x reference)
//
#include <hip/hip_runtime.h>
#include <stdint.h>

// Problem constants
#define T_SEQ 1024
#define B_SZ  16
#define C_IN  1024
#define C_HID 1024
#define M_ROWS (T_SEQ * B_SZ)   // 16384
#define N_COLS (2 * C_HID)      // 2048  (Z cols 0..1023, F cols 1024..2047)
#define K_DIM  (2 * C_IN)       // 2048  (k=0 half: X[t-1], k=1 half: X[t])

typedef __attribute__((ext_vector_type(8))) short bf16x8;
typedef __attribute__((ext_vector_type(4))) float f32x4;
typedef unsigned short u16;

__device__ __forceinline__ u16 f2bf(float f) {
  union { float f; unsigned u; } v; v.f = f;
  unsigned r = v.u + 0x7fffu + ((v.u >> 16) & 1u);  // RNE
  return (u16)(r >> 16);
}
__device__ __forceinline__ float bf2f(u16 s) {
  union { unsigned u; float f; } v; v.u = ((unsigned)s) << 16;
  return v.f;
}

// async global->LDS, 16B per lane. LDS dest must be wave-uniform base.
__device__ __forceinline__ void async_cp16(const u16* g, u16* l) {
  __builtin_amdgcn_global_load_lds(
      (const __attribute__((address_space(1))) unsigned*)(uintptr_t)g,
      (__attribute__((address_space(3))) unsigned*)(uintptr_t)l,
      16, 0, 0);
}

// ---------------------------------------------------------------------------
// Kernel 1: convert X (f32) -> bf16 with one leading zero time-step of padding.
// Xp layout: rows 0..B_SZ-1 are zeros (t = -1), then X rows (t*B + b).
// ---------------------------------------------------------------------------
__global__ void k_convert_x(const float* __restrict__ X, u16* __restrict__ Xp) {
  int i = blockIdx.x * 256 + threadIdx.x;       // one thread = 4 elems
  const int total4 = (M_ROWS + B_SZ) * C_IN / 4;  // 4,198,400
  if (i >= total4) return;
  int e = i << 2;
  const int PAD = B_SZ * C_IN;  // 16384
  ushort4 o;
  if (e < PAD) {
    o.x = o.y = o.z = o.w = 0;
  } else {
    float4 v = *reinterpret_cast<const float4*>(X + (e - PAD));
    o.x = f2bf(v.x); o.y = f2bf(v.y); o.z = f2bf(v.z); o.w = f2bf(v.w);
  }
  *reinterpret_cast<ushort4*>(Xp + e) = o;
}

// ---------------------------------------------------------------------------
// Kernel 2: repack Wz/Wf (HID, IN, K) f32 -> Wt (N=2048, K=2048) bf16, B^T form:
//   Wt[n][kk] with n = g*1024 + h, kk = k*1024 + c  =  W_g[h][c][k]
// ---------------------------------------------------------------------------
__global__ void k_repack_w(const float* __restrict__ Wz, const float* __restrict__ Wf,
                           u16* __restrict__ Wt) {
  int i = blockIdx.x * 256 + threadIdx.x;       // one thread = one (g,h,c)
  if (i >= 2 * 1024 * 1024) return;
  int g  = i >> 20;
  int hc = i & ((1 << 20) - 1);
  int h  = hc >> 10;
  int c  = hc & 1023;
  const float* W = g ? Wf : Wz;
  float2 w = *reinterpret_cast<const float2*>(W + ((size_t)(h << 10) + c) * 2);
  size_t n = (size_t)(g << 10) + h;
  Wt[n * K_DIM + c]        = f2bf(w.x);   // k = 0  (X[t-1] half)
  Wt[n * K_DIM + 1024 + c] = f2bf(w.y);   // k = 1  (X[t] half)
}

// ---------------------------------------------------------------------------
// Kernel 3: bf16 GEMM, m97 structure: 128x128 tile, BK=64, 4 waves,
// mfma_f32_16x16x32_bf16, global_load_lds width 16, 2-barrier K loop.
// C[m][n] = sum_kk A[m][kk] * Wt[n][kk], written as bf16 pre-activations.
// A[m][kk]: kk<1024 -> Xp row m (i.e. X[t-1,b]); kk>=1024 -> Xp row m+B_SZ.
// ---------------------------------------------------------------------------
__global__ __launch_bounds__(256, 2) void k_gemm(const u16* __restrict__ Xp,
                                                 const u16* __restrict__ Wt,
                                                 u16* __restrict__ Cb) {
  __shared__ u16 sA[128 * 64];
  __shared__ u16 sB[128 * 64];
  const int tid  = threadIdx.x;
  const int wid  = tid >> 6;
  const int lane = tid & 63;
  const int m0 = blockIdx.x << 7;
  const int n0 = blockIdx.y << 7;
  const int wr = wid >> 1, wc = wid & 1;

  f32x4 acc[4][4] = {};

  // staging coords: each wave stages 32 rows (4 issues of 8 rows x 64 cols)
  const int srow = (wid << 5) + (lane >> 3);
  const int scol = (lane & 7) << 3;
  // fragment coords
  const int lr = lane & 15;
  const int lk = (lane >> 4) << 3;

  u16* lA = &sA[(wid << 5) << 6];
  u16* lB = &sB[(wid << 5) << 6];

  for (int kt = 0; kt < 32; ++kt) {
    const u16* gA = Xp + (size_t)(m0 + ((kt >= 16) ? B_SZ : 0) + srow) * C_IN
                       + ((kt & 15) << 6) + scol;
    const u16* gB = Wt + (size_t)(n0 + srow) * K_DIM + (kt << 6) + scol;
#pragma unroll
    for (int i = 0; i < 4; ++i) {
      async_cp16(gA + (size_t)(i << 3) * C_IN, lA + ((i << 3) << 6));
      async_cp16(gB + (size_t)(i << 3) * K_DIM, lB + ((i << 3) << 6));
    }
    __syncthreads();  // drains vmcnt before barrier -> staging visible

#pragma unroll
    for (int ks = 0; ks < 2; ++ks) {
      bf16x8 a[4], b[4];
#pragma unroll
      for (int mi = 0; mi < 4; ++mi)
        a[mi] = *reinterpret_cast<const bf16x8*>(
            &sA[(((wr << 6) + (mi << 4) + lr) << 6) + (ks << 5) + lk]);
#pragma unroll
      for (int ni = 0; ni < 4; ++ni)
        b[ni] = *reinterpret_cast<const bf16x8*>(
            &sB[(((wc << 6) + (ni << 4) + lr) << 6) + (ks << 5) + lk]);
#pragma unroll
      for (int mi = 0; mi < 4; ++mi)
#pragma unroll
        for (int ni = 0; ni < 4; ++ni)
          acc[mi][ni] = __builtin_amdgcn_mfma_f32_16x16x32_bf16(
              a[mi], b[ni], acc[mi][ni], 0, 0, 0);
    }
    __syncthreads();
  }

  // epilogue: C/D layout col=lane&15, row=(lane>>4)*4+r  (m89-verified)
  const int erow = (lane >> 4) << 2;
  const int ecol = lane & 15;
#pragma unroll
  for (int mi = 0; mi < 4; ++mi) {
#pragma unroll
    for (int ni = 0; ni < 4; ++ni) {
      int row = m0 + (wr << 6) + (mi << 4) + erow;
      int col = n0 + (wc << 6) + (ni << 4) + ecol;
#pragma unroll
      for (int r = 0; r < 4; ++r)
        Cb[(size_t)(row + r) * N_COLS + col] = f2bf(acc[mi][ni][r]);
    }
  }
}

// ---------------------------------------------------------------------------
// Kernel 4: fused bias + quick_gelu/sigmoid + linear recurrence scan.
// One thread per (b,h) channel; 1024 serial steps; loads are t-indexed
// (independent of the carried h) so the compiler can pipeline them.
// out[0:M*1024] = H, out[M*1024:] = H[-1].
// ---------------------------------------------------------------------------
__global__ __launch_bounds__(64, 1) void k_scan(const u16* __restrict__ Cb,
                                                const float* __restrict__ bz,
                                                const float* __restrict__ bfv,
                                                float* __restrict__ out) {
  int c2 = blockIdx.x * 64 + threadIdx.x;  // 0..16383
  int b  = c2 >> 10;
  int hh = c2 & 1023;
  float biasz = bz[hh], biasf = bfv[hh];
  float h = 0.f;
  const size_t base = (size_t)b * N_COLS + hh;
  float* outp = out + (size_t)b * C_HID + hh;

#pragma unroll 8
  for (int t = 0; t < T_SEQ; ++t) {
    size_t off = base + (size_t)t * B_SZ * N_COLS;
    float z = bf2f(Cb[off]) + biasz;
    float f = bf2f(Cb[off + C_HID]) + biasf;
    z = z / (1.f + __expf(-1.702f * z));   // quick_gelu
    f = 1.f / (1.f + __expf(-f));          // sigmoid
    h = h + f * (z - h);                   // h = f*z + (1-f)*h
    outp[(size_t)t * B_SZ * C_HID] = h;
  }
  out[(size_t)M_ROWS * C_HID + c2] = h;    // H[-1]
}

// ---------------------------------------------------------------------------
extern "C" void kernel_launch(void* const* d_in, const int* in_sizes, int n_in,
                              void* d_out, int out_size, void* d_ws, size_t ws_size,
                              hipStream_t stream) {
  const float* X   = (const float*)d_in[0];
  const float* Wz  = (const float*)d_in[1];
  const float* bz  = (const float*)d_in[2];
  const float* Wf  = (const float*)d_in[3];
  const float* bf_ = (const float*)d_in[4];
  float* out = (float*)d_out;

  // workspace layout (bf16 = u16):
  u16* Xp = (u16*)d_ws;                                 // (16384+16)*1024
  u16* Wt = Xp + (size_t)(M_ROWS + B_SZ) * C_IN;        // 2048*2048
  u16* Cb = Wt + (size_t)N_COLS * K_DIM;                // 16384*2048
  // total = 109,084,672 bytes

  hipLaunchKernelGGL(k_convert_x, dim3(16400), dim3(256), 0, stream, X, Xp);
  hipLaunchKernelGGL(k_repack_w, dim3(8192), dim3(256), 0, stream, Wz, Wf, Wt);
  hipLaunchKernelGGL(k_gemm, dim3(M_ROWS / 128, N_COLS / 128), dim3(256), 0, stream,
                     Xp, Wt, Cb);
  hipLaunchKernelGGL(k_scan, dim3(M_ROWS / 64), dim3(64), 0, stream, Cb, bz, bf_, out);
}

// Round 3
// 328.673 us; speedup vs baseline: 1.2128x; 1.2128x over previous
//
#include <hip/hip_runtime.h>
#include <stdint.h>

// Problem constants
#define T_SEQ 1024
#define B_SZ  16
#define C_IN  1024
#define C_HID 1024
#define M_ROWS (T_SEQ * B_SZ)   // 16384
#define N_COLS (2 * C_HID)      // 2048  (col 2h = Z_h, col 2h+1 = F_h)
#define K_DIM  (2 * C_IN)       // 2048  (k<1024: X[t-1], k>=1024: X[t])

#define NCHUNK 16
#define CLEN   (T_SEQ / NCHUNK) // 64
#define NBH    (B_SZ * C_HID)   // 16384 channels

typedef __attribute__((ext_vector_type(8))) short bf16x8;
typedef __attribute__((ext_vector_type(4))) float f32x4;
typedef unsigned short u16;

__device__ __forceinline__ u16 f2bf(float f) {
  union { float f; unsigned u; } v; v.f = f;
  unsigned r = v.u + 0x7fffu + ((v.u >> 16) & 1u);  // RNE
  return (u16)(r >> 16);
}
__device__ __forceinline__ float bf2f(unsigned s) {
  union { unsigned u; float f; } v; v.u = s << 16;
  return v.f;
}

// async global->LDS, 16B per lane. LDS dest must be wave-uniform base.
__device__ __forceinline__ void async_cp16(const u16* g, u16* l) {
  __builtin_amdgcn_global_load_lds(
      (const __attribute__((address_space(1))) unsigned*)(uintptr_t)g,
      (__attribute__((address_space(3))) unsigned*)(uintptr_t)l,
      16, 0, 0);
}

// ---------------------------------------------------------------------------
// Kernel 1: convert X (f32) -> bf16 with one leading zero time-step of padding.
// Xp rows 0..B-1 are zeros (t=-1), then X rows (t*B+b).
// ---------------------------------------------------------------------------
__global__ void k_convert_x(const float* __restrict__ X, u16* __restrict__ Xp) {
  int i = blockIdx.x * 256 + threadIdx.x;         // one thread = 4 elems
  const int total4 = (M_ROWS + B_SZ) * C_IN / 4;  // 4,198,400
  if (i >= total4) return;
  int e = i << 2;
  const int PAD = B_SZ * C_IN;  // 16384
  ushort4 o;
  if (e < PAD) {
    o.x = o.y = o.z = o.w = 0;
  } else {
    float4 v = *reinterpret_cast<const float4*>(X + (e - PAD));
    o.x = f2bf(v.x); o.y = f2bf(v.y); o.z = f2bf(v.z); o.w = f2bf(v.w);
  }
  *reinterpret_cast<ushort4*>(Xp + e) = o;
}

// ---------------------------------------------------------------------------
// Kernel 2: repack Wz/Wf (HID, IN, K) f32 -> Wt (N=2048, K=2048) bf16, B^T,
// Z/F interleaved: row n = 2h is Wz[h], row n = 2h+1 is Wf[h].
// Wt[n][kk]: kk = c is the k=0 (X[t-1]) tap, kk = 1024+c is the k=1 tap.
// ---------------------------------------------------------------------------
__global__ void k_repack_w(const float* __restrict__ Wz, const float* __restrict__ Wf,
                           u16* __restrict__ Wt) {
  int i = blockIdx.x * 256 + threadIdx.x;  // one thread = one (g,h,c)
  if (i >= 2 * 1024 * 1024) return;
  int g  = i >> 20;
  int hc = i & ((1 << 20) - 1);
  int h  = hc >> 10;
  int c  = hc & 1023;
  const float* W = g ? Wf : Wz;
  float2 w = *reinterpret_cast<const float2*>(W + ((size_t)(h << 10) + c) * 2);
  size_t n = ((size_t)h << 1) | (size_t)g;   // interleave Z/F
  Wt[n * K_DIM + c]        = f2bf(w.x);      // k = 0 tap
  Wt[n * K_DIM + 1024 + c] = f2bf(w.y);      // k = 1 tap
}

// ---------------------------------------------------------------------------
// Kernel 3: bf16 GEMM (m97 structure) with fused bias + activation epilogue.
// Cb[m][2h]   = quick_gelu(Z[m][h] + bz[h])   (bf16)
// Cb[m][2h+1] = sigmoid  (F[m][h] + bf[h])    (bf16)
// ---------------------------------------------------------------------------
__global__ __launch_bounds__(256, 2) void k_gemm(const u16* __restrict__ Xp,
                                                 const u16* __restrict__ Wt,
                                                 const float* __restrict__ bz,
                                                 const float* __restrict__ bfv,
                                                 u16* __restrict__ Cb) {
  __shared__ u16 sA[128 * 64];
  __shared__ u16 sB[128 * 64];
  const int tid  = threadIdx.x;
  const int wid  = tid >> 6;
  const int lane = tid & 63;
  const int m0 = blockIdx.x << 7;
  const int n0 = blockIdx.y << 7;
  const int wr = wid >> 1, wc = wid & 1;

  f32x4 acc[4][4] = {};

  const int srow = (wid << 5) + (lane >> 3);  // staging row within tile
  const int scol = (lane & 7) << 3;           // staging col (x8 u16)
  const int lr = lane & 15;                   // fragment row
  const int lk = (lane >> 4) << 3;            // fragment k

  u16* lA = &sA[(wid << 5) << 6];
  u16* lB = &sB[(wid << 5) << 6];

  for (int kt = 0; kt < 32; ++kt) {
    const u16* gA = Xp + (size_t)(m0 + ((kt >= 16) ? B_SZ : 0) + srow) * C_IN
                       + ((kt & 15) << 6) + scol;
    const u16* gB = Wt + (size_t)(n0 + srow) * K_DIM + (kt << 6) + scol;
#pragma unroll
    for (int i = 0; i < 4; ++i) {
      async_cp16(gA + (size_t)(i << 3) * C_IN, lA + ((i << 3) << 6));
      async_cp16(gB + (size_t)(i << 3) * K_DIM, lB + ((i << 3) << 6));
    }
    __syncthreads();

#pragma unroll
    for (int ks = 0; ks < 2; ++ks) {
      bf16x8 a[4], b[4];
#pragma unroll
      for (int mi = 0; mi < 4; ++mi)
        a[mi] = *reinterpret_cast<const bf16x8*>(
            &sA[(((wr << 6) + (mi << 4) + lr) << 6) + (ks << 5) + lk]);
#pragma unroll
      for (int ni = 0; ni < 4; ++ni)
        b[ni] = *reinterpret_cast<const bf16x8*>(
            &sB[(((wc << 6) + (ni << 4) + lr) << 6) + (ks << 5) + lk]);
#pragma unroll
      for (int mi = 0; mi < 4; ++mi)
#pragma unroll
        for (int ni = 0; ni < 4; ++ni)
          acc[mi][ni] = __builtin_amdgcn_mfma_f32_16x16x32_bf16(
              a[mi], b[ni], acc[mi][ni], 0, 0, 0);
    }
    __syncthreads();
  }

  // epilogue: C/D layout col=lane&15, row=(lane>>4)*4+r  (m89-verified)
  const int erow = (lane >> 4) << 2;
  const int ecol = lane & 15;
#pragma unroll
  for (int ni = 0; ni < 4; ++ni) {
    int col  = n0 + (wc << 6) + (ni << 4) + ecol;
    int hcol = col >> 1;
    bool isz = (col & 1) == 0;            // lane-parity, wave-uniform per lane
    float bias = isz ? bz[hcol] : bfv[hcol];
    float kk   = isz ? 1.702f : 1.0f;
#pragma unroll
    for (int mi = 0; mi < 4; ++mi) {
      int row = m0 + (wr << 6) + (mi << 4) + erow;
#pragma unroll
      for (int r = 0; r < 4; ++r) {
        float v = acc[mi][ni][r] + bias;
        float s = 1.f / (1.f + __expf(-kk * v));
        float res = isz ? v * s : s;      // quick_gelu : sigmoid
        Cb[(size_t)(row + r) * N_COLS + col] = f2bf(res);
      }
    }
  }
}

// ---------------------------------------------------------------------------
// Chunked scan. h_t = f*z + (1-f)*h  is affine in h_start:
//   over a chunk: h_end = A + B*h_start,  B = prod(1-f).
// Pass 1: per (chunk,b,h) compute (A,B) with h_start=0.
// ---------------------------------------------------------------------------
__global__ __launch_bounds__(256) void k_scan1(const u16* __restrict__ Cb,
                                               float* __restrict__ Ap,
                                               float* __restrict__ Bp) {
  int i = blockIdx.x * 256 + threadIdx.x;  // 262144 = NCHUNK * NBH
  int h = i & (C_HID - 1);
  int b = (i >> 10) & (B_SZ - 1);
  int c = i >> 14;
  const unsigned* Cu = (const unsigned*)Cb;  // u32 = (z | f<<16)
  size_t base = (size_t)b * C_HID + h + (size_t)c * CLEN * NBH;
  float hh = 0.f, P = 1.f;
#pragma unroll 16
  for (int t = 0; t < CLEN; ++t) {
    unsigned zf = Cu[base + (size_t)t * NBH];
    float z = bf2f(zf & 0xffffu);
    float f = bf2f(zf >> 16);
    hh += f * (z - hh);
    P  *= (1.f - f);
  }
  Ap[i] = hh;
  Bp[i] = P;
}

// Pass 2: per (b,h), combine the NCHUNK affine maps; emit per-chunk h_start.
__global__ __launch_bounds__(256) void k_scan2(const float* __restrict__ Ap,
                                               const float* __restrict__ Bp,
                                               float* __restrict__ St) {
  int i = blockIdx.x * 256 + threadIdx.x;  // 16384 = NBH
  float hh = 0.f;
#pragma unroll
  for (int c = 0; c < NCHUNK; ++c) {
    St[c * NBH + i] = hh;
    hh = Ap[c * NBH + i] + Bp[c * NBH + i] * hh;
  }
}

// Pass 3: re-run each chunk from its correct start state, write H (+ tail).
__global__ __launch_bounds__(256) void k_scan3(const u16* __restrict__ Cb,
                                               const float* __restrict__ St,
                                               float* __restrict__ out) {
  int i = blockIdx.x * 256 + threadIdx.x;  // 262144
  int bh = i & (NBH - 1);
  int c = i >> 14;
  const unsigned* Cu = (const unsigned*)Cb;
  size_t base = (size_t)bh + (size_t)c * CLEN * NBH;
  float hh = St[i];  // St[c*NBH + bh] == St[i]
#pragma unroll 16
  for (int t = 0; t < CLEN; ++t) {
    unsigned zf = Cu[base + (size_t)t * NBH];
    float z = bf2f(zf & 0xffffu);
    float f = bf2f(zf >> 16);
    hh += f * (z - hh);
    out[base + (size_t)t * NBH] = hh;    // out[(t_global*B+b)*H + h]
  }
  if (c == NCHUNK - 1)
    out[(size_t)M_ROWS * C_HID + bh] = hh;  // H[-1]
}

// ---------------------------------------------------------------------------
extern "C" void kernel_launch(void* const* d_in, const int* in_sizes, int n_in,
                              void* d_out, int out_size, void* d_ws, size_t ws_size,
                              hipStream_t stream) {
  const float* X   = (const float*)d_in[0];
  const float* Wz  = (const float*)d_in[1];
  const float* bz  = (const float*)d_in[2];
  const float* Wf  = (const float*)d_in[3];
  const float* bf_ = (const float*)d_in[4];
  float* out = (float*)d_out;

  // workspace layout (bf16 = u16):
  u16* Xp = (u16*)d_ws;                                 // (16384+16)*1024 u16
  u16* Wt = Xp + (size_t)(M_ROWS + B_SZ) * C_IN;        // 2048*2048 u16
  u16* Cb = Wt + (size_t)N_COLS * K_DIM;                // 16384*2048 u16
  // scan scratch reuses the (dead after GEMM) Xp region: 3 MB << 33 MB
  float* Ap = (float*)Xp;                               // NCHUNK*NBH f32
  float* Bp = Ap + NCHUNK * NBH;
  float* St = Bp + NCHUNK * NBH;

  hipLaunchKernelGGL(k_convert_x, dim3(16400), dim3(256), 0, stream, X, Xp);
  hipLaunchKernelGGL(k_repack_w, dim3(8192), dim3(256), 0, stream, Wz, Wf, Wt);
  hipLaunchKernelGGL(k_gemm, dim3(M_ROWS / 128, N_COLS / 128), dim3(256), 0, stream,
                     Xp, Wt, bz, bf_, Cb);
  hipLaunchKernelGGL(k_scan1, dim3(NCHUNK * NBH / 256), dim3(256), 0, stream,
                     Cb, Ap, Bp);
  hipLaunchKernelGGL(k_scan2, dim3(NBH / 256), dim3(256), 0, stream, Ap, Bp, St);
  hipLaunchKernelGGL(k_scan3, dim3(NCHUNK * NBH / 256), dim3(256), 0, stream,
                     Cb, St, out);
}

// Round 4
// 308.132 us; speedup vs baseline: 1.2936x; 1.0667x over previous
//
#include <hip/hip_runtime.h>
#include <stdint.h>

// Problem constants
#define T_SEQ 1024
#define B_SZ  16
#define C_IN  1024
#define C_HID 1024
#define M_ROWS (T_SEQ * B_SZ)   // 16384
#define N_COLS (2 * C_HID)      // 2048  (col 2h = Z_h, col 2h+1 = F_h)
#define K_DIM  (2 * C_IN)       // 2048  (k<1024: X[t-1], k>=1024: X[t])

#define NCHUNK 16
#define CLEN   (T_SEQ / NCHUNK) // 64
#define NBH    (B_SZ * C_HID)   // 16384 channels

typedef __attribute__((ext_vector_type(8))) short bf16x8;
typedef __attribute__((ext_vector_type(4))) float f32x4;
typedef unsigned short u16;

#define MFMA __builtin_amdgcn_mfma_f32_16x16x32_bf16

__device__ __forceinline__ u16 f2bf(float f) {
  union { float f; unsigned u; } v; v.f = f;
  unsigned r = v.u + 0x7fffu + ((v.u >> 16) & 1u);  // RNE
  return (u16)(r >> 16);
}
__device__ __forceinline__ float bf2f(unsigned s) {
  union { unsigned u; float f; } v; v.u = s << 16;
  return v.f;
}

// async global->LDS, 16B per lane. LDS dest is wave-uniform base + lane*16.
__device__ __forceinline__ void async_cp16(const u16* g, u16* l) {
  __builtin_amdgcn_global_load_lds(
      (const __attribute__((address_space(1))) unsigned*)(uintptr_t)g,
      (__attribute__((address_space(3))) unsigned*)(uintptr_t)l,
      16, 0, 0);
}

// ---------------------------------------------------------------------------
// Kernel 1: convert X (f32) -> bf16 with one leading zero time-step of padding.
// ---------------------------------------------------------------------------
__global__ void k_convert_x(const float* __restrict__ X, u16* __restrict__ Xp) {
  int i = blockIdx.x * 256 + threadIdx.x;         // one thread = 4 elems
  const int total4 = (M_ROWS + B_SZ) * C_IN / 4;
  if (i >= total4) return;
  int e = i << 2;
  const int PAD = B_SZ * C_IN;  // 16384
  ushort4 o;
  if (e < PAD) {
    o.x = o.y = o.z = o.w = 0;
  } else {
    float4 v = *reinterpret_cast<const float4*>(X + (e - PAD));
    o.x = f2bf(v.x); o.y = f2bf(v.y); o.z = f2bf(v.z); o.w = f2bf(v.w);
  }
  *reinterpret_cast<ushort4*>(Xp + e) = o;
}

// ---------------------------------------------------------------------------
// Kernel 2: repack Wz/Wf -> Wt (N=2048, K=2048) bf16, B^T, Z/F interleaved.
// ---------------------------------------------------------------------------
__global__ void k_repack_w(const float* __restrict__ Wz, const float* __restrict__ Wf,
                           u16* __restrict__ Wt) {
  int i = blockIdx.x * 256 + threadIdx.x;  // one thread = one (g,h,c)
  if (i >= 2 * 1024 * 1024) return;
  int g  = i >> 20;
  int hc = i & ((1 << 20) - 1);
  int h  = hc >> 10;
  int c  = hc & 1023;
  const float* W = g ? Wf : Wz;
  float2 w = *reinterpret_cast<const float2*>(W + ((size_t)(h << 10) + c) * 2);
  size_t n = ((size_t)h << 1) | (size_t)g;   // interleave Z/F
  Wt[n * K_DIM + c]        = f2bf(w.x);      // k = 0 tap
  Wt[n * K_DIM + 1024 + c] = f2bf(w.y);      // k = 1 tap
}

// ---------------------------------------------------------------------------
// Kernel 3: 256x256-tile 8-phase bf16 GEMM (T1+T2+T3/T4+T5), fused activation.
//   C[m][n] = sum_kk A[m][kk] * Wt[n][kk]
//   A[m][kk]: kk<1024 -> Xp row m, col kk; kk>=1024 -> Xp row m+B_SZ, col kk-1024.
// 8 waves (2M x 4N); per-wave 128x64 output; BK=64; 4 phases/K-tile.
// LDS swizzle: byte ^= (row&7)<<4 (both-sides: pre-swizzled global source for
// the linear global_load_lds dest, swizzled ds_read address).
// Half-tile stream order per K-tile: [B0,B1,A0,A1]; one half staged per phase,
// 7 halves ahead; vmcnt(6) once per K-tile.
// ---------------------------------------------------------------------------
__global__ __launch_bounds__(512, 2) void k_gemm8(const u16* __restrict__ Xp,
                                                  const u16* __restrict__ Wt,
                                                  const float* __restrict__ bz,
                                                  const float* __restrict__ bfv,
                                                  u16* __restrict__ Cb) {
  __shared__ u16 lds[2][2][2][8192];  // [buf][A=0/B=1][half][128*64] = 128 KiB
  const int tid  = threadIdx.x;
  const int lane = tid & 63;
  const int wid  = tid >> 6;
  const int wr = wid >> 2;        // m-half of this wave
  const int wc = wid & 3;         // n-quarter
  const int lr = lane & 15;

  // T1: XCD-bijective swizzle (512 blocks, 512%8==0), n-fastest within XCD
  int wg = (blockIdx.x & 7) * 64 + (blockIdx.x >> 3);
  const int m0 = (wg >> 3) << 8;
  const int n0 = (wg & 7) << 8;

  // staging per-thread coords: linear LDS byte p -> logical source byte q
  const int p    = tid << 4;
  const int q    = p ^ (((p >> 7) & 7) << 4);   // involution (bits 4-6 vs 7-9)
  const int grow = q >> 7;                      // logical row 0..63 (issue 0)
  const int gcol = (q & 127) >> 1;              // logical col element
  const int ldsw = (tid >> 6) << 9;             // u16 wave base (wid*1KB)

  // ds_read per-thread coords (u16 units), swizzled column offset
  const int rbase = lr << 6;
  int co[2];
#pragma unroll
  for (int ks = 0; ks < 2; ++ks)
    co[ks] = ((((ks << 6) | ((lane >> 4) << 4)) ^ ((lr & 7) << 4)) >> 1);

  auto stage = [&](int j) {   // j = 4*kt + {0:B0,1:B1,2:A0,3:A1}
    int kt = j >> 2, part = j & 3, buf = kt & 1;
    if (part >= 2) {
      int h = part - 2;
      const u16* g = Xp + (size_t)(m0 + (h << 7) + grow + ((kt >= 16) ? B_SZ : 0)) * C_IN
                        + ((kt & 15) << 6) + gcol;
      u16* l = &lds[buf][0][h][ldsw];
      async_cp16(g, l);
      async_cp16(g + (size_t)64 * C_IN, l + 4096);
    } else {
      const u16* g = Wt + (size_t)(n0 + (part << 7) + grow) * K_DIM + (kt << 6) + gcol;
      u16* l = &lds[buf][1][part][ldsw];
      async_cp16(g, l);
      async_cp16(g + (size_t)64 * K_DIM, l + 4096);
    }
  };

  f32x4 acc[8][4] = {};
  bf16x8 a[4][2], b0[2][2], b1[2][2];

  // prologue: tile0 all halves + tile1 B0,B1,A0  (j0..6); tile0 ready at vmcnt(6)
  for (int j = 0; j < 7; ++j) stage(j);
  asm volatile("s_waitcnt vmcnt(6)" ::: "memory");
  __builtin_amdgcn_s_barrier();

#pragma unroll 2
  for (int t = 0; t < 32; ++t) {
    const int buf = t & 1;
    const u16* pA = &lds[buf][0][wr][0];
    const u16* pB = &lds[buf][1][wc >> 1][(wc & 1) << 12];
    const int jb = 4 * t + 7;

    // ---- P1: read a(s=0)+b0; stage; mfma Q(0,0)
#pragma unroll
    for (int mi = 0; mi < 4; ++mi)
#pragma unroll
      for (int ks = 0; ks < 2; ++ks)
        a[mi][ks] = *(const bf16x8*)(pA + (mi << 10) + rbase + co[ks]);
#pragma unroll
    for (int ni = 0; ni < 2; ++ni)
#pragma unroll
      for (int ks = 0; ks < 2; ++ks)
        b0[ni][ks] = *(const bf16x8*)(pB + (ni << 10) + rbase + co[ks]);
    if (jb < 128) stage(jb);
    __builtin_amdgcn_s_barrier();
    asm volatile("s_waitcnt lgkmcnt(0)" ::: "memory");
    __builtin_amdgcn_s_setprio(1);
#pragma unroll
    for (int mi = 0; mi < 4; ++mi)
#pragma unroll
      for (int ni = 0; ni < 2; ++ni)
#pragma unroll
        for (int ks = 0; ks < 2; ++ks)
          acc[mi][ni] = MFMA(a[mi][ks], b0[ni][ks], acc[mi][ni], 0, 0, 0);
    __builtin_amdgcn_s_setprio(0);
    __builtin_amdgcn_s_barrier();

    // ---- P2: read b1; stage; mfma Q(0,1)
#pragma unroll
    for (int ni = 0; ni < 2; ++ni)
#pragma unroll
      for (int ks = 0; ks < 2; ++ks)
        b1[ni][ks] = *(const bf16x8*)(pB + ((2 + ni) << 10) + rbase + co[ks]);
    if (jb + 1 < 128) stage(jb + 1);
    __builtin_amdgcn_s_barrier();
    asm volatile("s_waitcnt lgkmcnt(0)" ::: "memory");
    __builtin_amdgcn_s_setprio(1);
#pragma unroll
    for (int mi = 0; mi < 4; ++mi)
#pragma unroll
      for (int ni = 0; ni < 2; ++ni)
#pragma unroll
        for (int ks = 0; ks < 2; ++ks)
          acc[mi][2 + ni] = MFMA(a[mi][ks], b1[ni][ks], acc[mi][2 + ni], 0, 0, 0);
    __builtin_amdgcn_s_setprio(0);
    __builtin_amdgcn_s_barrier();

    // ---- P3: read a(s=1); stage; mfma Q(1,1)
#pragma unroll
    for (int mi = 0; mi < 4; ++mi)
#pragma unroll
      for (int ks = 0; ks < 2; ++ks)
        a[mi][ks] = *(const bf16x8*)(pA + ((4 + mi) << 10) + rbase + co[ks]);
    if (jb + 2 < 128) stage(jb + 2);
    __builtin_amdgcn_s_barrier();
    asm volatile("s_waitcnt lgkmcnt(0)" ::: "memory");
    __builtin_amdgcn_s_setprio(1);
#pragma unroll
    for (int mi = 0; mi < 4; ++mi)
#pragma unroll
      for (int ni = 0; ni < 2; ++ni)
#pragma unroll
        for (int ks = 0; ks < 2; ++ks)
          acc[4 + mi][2 + ni] = MFMA(a[mi][ks], b1[ni][ks], acc[4 + mi][2 + ni], 0, 0, 0);
    __builtin_amdgcn_s_setprio(0);
    __builtin_amdgcn_s_barrier();

    // ---- P4: no reads (b0 kept in regs); stage; vmcnt; mfma Q(1,0)
    if (jb + 3 < 128) stage(jb + 3);
    if (t < 30) asm volatile("s_waitcnt vmcnt(6)" ::: "memory");
    else        asm volatile("s_waitcnt vmcnt(0)" ::: "memory");
    __builtin_amdgcn_s_barrier();
    __builtin_amdgcn_s_setprio(1);
#pragma unroll
    for (int mi = 0; mi < 4; ++mi)
#pragma unroll
      for (int ni = 0; ni < 2; ++ni)
#pragma unroll
        for (int ks = 0; ks < 2; ++ks)
          acc[4 + mi][ni] = MFMA(a[mi][ks], b0[ni][ks], acc[4 + mi][ni], 0, 0, 0);
    __builtin_amdgcn_s_setprio(0);
    __builtin_amdgcn_s_barrier();
  }

  // epilogue: C/D layout col=lane&15, row=(lane>>4)*4+r; fused bias+activation
  const int erow = (lane >> 4) << 2;
  const int ecol = lane & 15;
#pragma unroll
  for (int ni = 0; ni < 4; ++ni) {
    int col  = n0 + (wc << 6) + (ni << 4) + ecol;
    int hcol = col >> 1;
    bool isz = (col & 1) == 0;
    float bias = isz ? bz[hcol] : bfv[hcol];
    float kk   = isz ? 1.702f : 1.0f;
#pragma unroll
    for (int mi = 0; mi < 8; ++mi) {
      int row = m0 + (wr << 7) + (mi << 4) + erow;
#pragma unroll
      for (int r = 0; r < 4; ++r) {
        float v = acc[mi][ni][r] + bias;
        float s = 1.f / (1.f + __expf(-kk * v));
        float res = isz ? v * s : s;      // quick_gelu : sigmoid
        Cb[(size_t)(row + r) * N_COLS + col] = f2bf(res);
      }
    }
  }
}

// ---------------------------------------------------------------------------
// Chunked scan (unchanged from round 3).
// ---------------------------------------------------------------------------
__global__ __launch_bounds__(256) void k_scan1(const u16* __restrict__ Cb,
                                               float* __restrict__ Ap,
                                               float* __restrict__ Bp) {
  int i = blockIdx.x * 256 + threadIdx.x;  // 262144 = NCHUNK * NBH
  int h = i & (C_HID - 1);
  int b = (i >> 10) & (B_SZ - 1);
  int c = i >> 14;
  const unsigned* Cu = (const unsigned*)Cb;  // u32 = (z | f<<16)
  size_t base = (size_t)b * C_HID + h + (size_t)c * CLEN * NBH;
  float hh = 0.f, P = 1.f;
#pragma unroll 16
  for (int t = 0; t < CLEN; ++t) {
    unsigned zf = Cu[base + (size_t)t * NBH];
    float z = bf2f(zf & 0xffffu);
    float f = bf2f(zf >> 16);
    hh += f * (z - hh);
    P  *= (1.f - f);
  }
  Ap[i] = hh;
  Bp[i] = P;
}

__global__ __launch_bounds__(256) void k_scan2(const float* __restrict__ Ap,
                                               const float* __restrict__ Bp,
                                               float* __restrict__ St) {
  int i = blockIdx.x * 256 + threadIdx.x;  // 16384 = NBH
  float hh = 0.f;
#pragma unroll
  for (int c = 0; c < NCHUNK; ++c) {
    St[c * NBH + i] = hh;
    hh = Ap[c * NBH + i] + Bp[c * NBH + i] * hh;
  }
}

__global__ __launch_bounds__(256) void k_scan3(const u16* __restrict__ Cb,
                                               const float* __restrict__ St,
                                               float* __restrict__ out) {
  int i = blockIdx.x * 256 + threadIdx.x;  // 262144
  int bh = i & (NBH - 1);
  int c = i >> 14;
  const unsigned* Cu = (const unsigned*)Cb;
  size_t base = (size_t)bh + (size_t)c * CLEN * NBH;
  float hh = St[i];
#pragma unroll 16
  for (int t = 0; t < CLEN; ++t) {
    unsigned zf = Cu[base + (size_t)t * NBH];
    float z = bf2f(zf & 0xffffu);
    float f = bf2f(zf >> 16);
    hh += f * (z - hh);
    out[base + (size_t)t * NBH] = hh;
  }
  if (c == NCHUNK - 1)
    out[(size_t)M_ROWS * C_HID + bh] = hh;  // H[-1]
}

// ---------------------------------------------------------------------------
extern "C" void kernel_launch(void* const* d_in, const int* in_sizes, int n_in,
                              void* d_out, int out_size, void* d_ws, size_t ws_size,
                              hipStream_t stream) {
  const float* X   = (const float*)d_in[0];
  const float* Wz  = (const float*)d_in[1];
  const float* bz  = (const float*)d_in[2];
  const float* Wf  = (const float*)d_in[3];
  const float* bf_ = (const float*)d_in[4];
  float* out = (float*)d_out;

  // workspace layout (bf16 = u16):
  u16* Xp = (u16*)d_ws;                                 // (16384+16)*1024 u16
  u16* Wt = Xp + (size_t)(M_ROWS + B_SZ) * C_IN;        // 2048*2048 u16
  u16* Cb = Wt + (size_t)N_COLS * K_DIM;                // 16384*2048 u16
  // scan scratch reuses the (dead after GEMM) Xp region
  float* Ap = (float*)Xp;                               // NCHUNK*NBH f32
  float* Bp = Ap + NCHUNK * NBH;
  float* St = Bp + NCHUNK * NBH;

  hipLaunchKernelGGL(k_convert_x, dim3(16400), dim3(256), 0, stream, X, Xp);
  hipLaunchKernelGGL(k_repack_w, dim3(8192), dim3(256), 0, stream, Wz, Wf, Wt);
  hipLaunchKernelGGL(k_gemm8, dim3((M_ROWS / 256) * (N_COLS / 256)), dim3(512), 0,
                     stream, Xp, Wt, bz, bf_, Cb);
  hipLaunchKernelGGL(k_scan1, dim3(NCHUNK * NBH / 256), dim3(256), 0, stream,
                     Cb, Ap, Bp);
  hipLaunchKernelGGL(k_scan2, dim3(NBH / 256), dim3(256), 0, stream, Ap, Bp, St);
  hipLaunchKernelGGL(k_scan3, dim3(NCHUNK * NBH / 256), dim3(256), 0, stream,
                     Cb, St, out);
}

// Round 5
// 296.929 us; speedup vs baseline: 1.3425x; 1.0377x over previous
//
#include <hip/hip_runtime.h>
#include <stdint.h>

// Problem constants
#define T_SEQ 1024
#define B_SZ  16
#define C_IN  1024
#define C_HID 1024
#define M_ROWS (T_SEQ * B_SZ)   // 16384
#define N_COLS (2 * C_HID)      // 2048  (col 2h = Z_h, col 2h+1 = F_h)
#define K_DIM  (2 * C_IN)       // 2048  (k<1024: X[t-1], k>=1024: X[t])

#define NCHUNK 16
#define CLEN   (T_SEQ / NCHUNK) // 64
#define NBH    (B_SZ * C_HID)   // 16384 channels

typedef __attribute__((ext_vector_type(8))) short bf16x8;
typedef __attribute__((ext_vector_type(4))) float f32x4;
typedef unsigned short u16;

#define MFMA __builtin_amdgcn_mfma_f32_16x16x32_bf16

__device__ __forceinline__ u16 f2bf(float f) {
  union { float f; unsigned u; } v; v.f = f;
  unsigned r = v.u + 0x7fffu + ((v.u >> 16) & 1u);  // RNE
  return (u16)(r >> 16);
}
__device__ __forceinline__ float bf2f(unsigned s) {
  union { unsigned u; float f; } v; v.u = s << 16;
  return v.f;
}

// async global->LDS, 16B per lane. LDS dest is wave-uniform base + lane*16.
__device__ __forceinline__ void async_cp16(const u16* g, u16* l) {
  __builtin_amdgcn_global_load_lds(
      (const __attribute__((address_space(1))) unsigned*)(uintptr_t)g,
      (__attribute__((address_space(3))) unsigned*)(uintptr_t)l,
      16, 0, 0);
}

// ---------------------------------------------------------------------------
// Kernel 1: convert X (f32) -> bf16 with one leading zero time-step of padding.
// ---------------------------------------------------------------------------
__global__ void k_convert_x(const float* __restrict__ X, u16* __restrict__ Xp) {
  int i = blockIdx.x * 256 + threadIdx.x;         // one thread = 4 elems
  const int total4 = (M_ROWS + B_SZ) * C_IN / 4;
  if (i >= total4) return;
  int e = i << 2;
  const int PAD = B_SZ * C_IN;  // 16384
  ushort4 o;
  if (e < PAD) {
    o.x = o.y = o.z = o.w = 0;
  } else {
    float4 v = *reinterpret_cast<const float4*>(X + (e - PAD));
    o.x = f2bf(v.x); o.y = f2bf(v.y); o.z = f2bf(v.z); o.w = f2bf(v.w);
  }
  *reinterpret_cast<ushort4*>(Xp + e) = o;
}

// ---------------------------------------------------------------------------
// Kernel 2: repack Wz/Wf -> Wt (N=2048, K=2048) bf16, B^T, Z/F interleaved.
// ---------------------------------------------------------------------------
__global__ void k_repack_w(const float* __restrict__ Wz, const float* __restrict__ Wf,
                           u16* __restrict__ Wt) {
  int i = blockIdx.x * 256 + threadIdx.x;  // one thread = one (g,h,c)
  if (i >= 2 * 1024 * 1024) return;
  int g  = i >> 20;
  int hc = i & ((1 << 20) - 1);
  int h  = hc >> 10;
  int c  = hc & 1023;
  const float* W = g ? Wf : Wz;
  float2 w = *reinterpret_cast<const float2*>(W + ((size_t)(h << 10) + c) * 2);
  size_t n = ((size_t)h << 1) | (size_t)g;   // interleave Z/F
  Wt[n * K_DIM + c]        = f2bf(w.x);      // k = 0 tap
  Wt[n * K_DIM + 1024 + c] = f2bf(w.y);      // k = 1 tap
}

// ---------------------------------------------------------------------------
// Kernel 3: 256x256-tile 8-phase bf16 GEMM (T1+T2+T3/T4+T5), fused activation.
// K-loop identical to round 4 (verified: 0 bank conflicts).
// NEW epilogue: fragment-blocked Cb layout.
//   frag fi = (gm>>4)*128 + (gn>>4); element (lane, reg r) at Cb[fi*256+lane*4+r]
//   Each lane stores ushort4 (8B) -> 512B contiguous per wave per frag.
//   Since gm = t*16+b: frag-row == t, row16 == b, (lane>>4) == b>>2, r == b&3.
// ---------------------------------------------------------------------------
__global__ __launch_bounds__(512, 2) void k_gemm8(const u16* __restrict__ Xp,
                                                  const u16* __restrict__ Wt,
                                                  const float* __restrict__ bz,
                                                  const float* __restrict__ bfv,
                                                  u16* __restrict__ Cb) {
  __shared__ u16 lds[2][2][2][8192];  // [buf][A=0/B=1][half][128*64] = 128 KiB
  const int tid  = threadIdx.x;
  const int lane = tid & 63;
  const int wid  = tid >> 6;
  const int wr = wid >> 2;        // m-half of this wave
  const int wc = wid & 3;         // n-quarter
  const int lr = lane & 15;

  // T1: XCD-bijective swizzle (512 blocks, 512%8==0), n-fastest within XCD
  int wg = (blockIdx.x & 7) * 64 + (blockIdx.x >> 3);
  const int m0 = (wg >> 3) << 8;
  const int n0 = (wg & 7) << 8;

  // staging per-thread coords: linear LDS byte p -> logical source byte q
  const int p    = tid << 4;
  const int q    = p ^ (((p >> 7) & 7) << 4);   // involution (bits 4-6 vs 7-9)
  const int grow = q >> 7;                      // logical row 0..63 (issue 0)
  const int gcol = (q & 127) >> 1;              // logical col element
  const int ldsw = (tid >> 6) << 9;             // u16 wave base (wid*1KB)

  // ds_read per-thread coords (u16 units), swizzled column offset
  const int rbase = lr << 6;
  int co[2];
#pragma unroll
  for (int ks = 0; ks < 2; ++ks)
    co[ks] = ((((ks << 6) | ((lane >> 4) << 4)) ^ ((lr & 7) << 4)) >> 1);

  auto stage = [&](int j) {   // j = 4*kt + {0:B0,1:B1,2:A0,3:A1}
    int kt = j >> 2, part = j & 3, buf = kt & 1;
    if (part >= 2) {
      int h = part - 2;
      const u16* g = Xp + (size_t)(m0 + (h << 7) + grow + ((kt >= 16) ? B_SZ : 0)) * C_IN
                        + ((kt & 15) << 6) + gcol;
      u16* l = &lds[buf][0][h][ldsw];
      async_cp16(g, l);
      async_cp16(g + (size_t)64 * C_IN, l + 4096);
    } else {
      const u16* g = Wt + (size_t)(n0 + (part << 7) + grow) * K_DIM + (kt << 6) + gcol;
      u16* l = &lds[buf][1][part][ldsw];
      async_cp16(g, l);
      async_cp16(g + (size_t)64 * K_DIM, l + 4096);
    }
  };

  f32x4 acc[8][4] = {};
  bf16x8 a[4][2], b0[2][2], b1[2][2];

  // prologue: tile0 all halves + tile1 B0,B1,A0  (j0..6); tile0 ready at vmcnt(6)
  for (int j = 0; j < 7; ++j) stage(j);
  asm volatile("s_waitcnt vmcnt(6)" ::: "memory");
  __builtin_amdgcn_s_barrier();

#pragma unroll 2
  for (int t = 0; t < 32; ++t) {
    const int buf = t & 1;
    const u16* pA = &lds[buf][0][wr][0];
    const u16* pB = &lds[buf][1][wc >> 1][(wc & 1) << 12];
    const int jb = 4 * t + 7;

    // ---- P1: read a(s=0)+b0; stage; mfma Q(0,0)
#pragma unroll
    for (int mi = 0; mi < 4; ++mi)
#pragma unroll
      for (int ks = 0; ks < 2; ++ks)
        a[mi][ks] = *(const bf16x8*)(pA + (mi << 10) + rbase + co[ks]);
#pragma unroll
    for (int ni = 0; ni < 2; ++ni)
#pragma unroll
      for (int ks = 0; ks < 2; ++ks)
        b0[ni][ks] = *(const bf16x8*)(pB + (ni << 10) + rbase + co[ks]);
    if (jb < 128) stage(jb);
    __builtin_amdgcn_s_barrier();
    asm volatile("s_waitcnt lgkmcnt(0)" ::: "memory");
    __builtin_amdgcn_s_setprio(1);
#pragma unroll
    for (int mi = 0; mi < 4; ++mi)
#pragma unroll
      for (int ni = 0; ni < 2; ++ni)
#pragma unroll
        for (int ks = 0; ks < 2; ++ks)
          acc[mi][ni] = MFMA(a[mi][ks], b0[ni][ks], acc[mi][ni], 0, 0, 0);
    __builtin_amdgcn_s_setprio(0);
    __builtin_amdgcn_s_barrier();

    // ---- P2: read b1; stage; mfma Q(0,1)
#pragma unroll
    for (int ni = 0; ni < 2; ++ni)
#pragma unroll
      for (int ks = 0; ks < 2; ++ks)
        b1[ni][ks] = *(const bf16x8*)(pB + ((2 + ni) << 10) + rbase + co[ks]);
    if (jb + 1 < 128) stage(jb + 1);
    __builtin_amdgcn_s_barrier();
    asm volatile("s_waitcnt lgkmcnt(0)" ::: "memory");
    __builtin_amdgcn_s_setprio(1);
#pragma unroll
    for (int mi = 0; mi < 4; ++mi)
#pragma unroll
      for (int ni = 0; ni < 2; ++ni)
#pragma unroll
        for (int ks = 0; ks < 2; ++ks)
          acc[mi][2 + ni] = MFMA(a[mi][ks], b1[ni][ks], acc[mi][2 + ni], 0, 0, 0);
    __builtin_amdgcn_s_setprio(0);
    __builtin_amdgcn_s_barrier();

    // ---- P3: read a(s=1); stage; mfma Q(1,1)
#pragma unroll
    for (int mi = 0; mi < 4; ++mi)
#pragma unroll
      for (int ks = 0; ks < 2; ++ks)
        a[mi][ks] = *(const bf16x8*)(pA + ((4 + mi) << 10) + rbase + co[ks]);
    if (jb + 2 < 128) stage(jb + 2);
    __builtin_amdgcn_s_barrier();
    asm volatile("s_waitcnt lgkmcnt(0)" ::: "memory");
    __builtin_amdgcn_s_setprio(1);
#pragma unroll
    for (int mi = 0; mi < 4; ++mi)
#pragma unroll
      for (int ni = 0; ni < 2; ++ni)
#pragma unroll
        for (int ks = 0; ks < 2; ++ks)
          acc[4 + mi][2 + ni] = MFMA(a[mi][ks], b1[ni][ks], acc[4 + mi][2 + ni], 0, 0, 0);
    __builtin_amdgcn_s_setprio(0);
    __builtin_amdgcn_s_barrier();

    // ---- P4: no reads (b0 kept in regs); stage; vmcnt; mfma Q(1,0)
    if (jb + 3 < 128) stage(jb + 3);
    if (t < 30) asm volatile("s_waitcnt vmcnt(6)" ::: "memory");
    else        asm volatile("s_waitcnt vmcnt(0)" ::: "memory");
    __builtin_amdgcn_s_barrier();
    __builtin_amdgcn_s_setprio(1);
#pragma unroll
    for (int mi = 0; mi < 4; ++mi)
#pragma unroll
      for (int ni = 0; ni < 2; ++ni)
#pragma unroll
        for (int ks = 0; ks < 2; ++ks)
          acc[4 + mi][ni] = MFMA(a[mi][ks], b0[ni][ks], acc[4 + mi][ni], 0, 0, 0);
    __builtin_amdgcn_s_setprio(0);
    __builtin_amdgcn_s_barrier();
  }

  // ---- Epilogue: fused bias+activation, fragment-blocked coalesced stores.
  // C/D frag layout: col16 = lane&15, row16 = (lane>>4)*4 + r.
  const int colp = lane & 15;
  const bool isz = (colp & 1) == 0;          // col parity == lane parity
  const float kk = isz ? 1.702f : 1.0f;
  const int hbase = (n0 + (wc << 6) + colp) >> 1;  // + 8*ni
  const int fmb = (m0 >> 4) + (wr << 3);
  const int fnb = (n0 >> 4) + (wc << 2);
#pragma unroll
  for (int ni = 0; ni < 4; ++ni) {
    float bias = isz ? bz[hbase + 8 * ni] : bfv[hbase + 8 * ni];
#pragma unroll
    for (int mi = 0; mi < 8; ++mi) {
      ushort4 o;
#pragma unroll
      for (int r = 0; r < 4; ++r) {
        float v = acc[mi][ni][r] + bias;
        float s = 1.f / (1.f + __expf(-kk * v));
        ((u16*)&o)[r] = f2bf(isz ? v * s : s);  // quick_gelu : sigmoid
      }
      size_t fi = (size_t)(fmb + mi) * 128 + (fnb + ni);
      *reinterpret_cast<ushort4*>(Cb + fi * 256 + (lane << 2)) = o;
    }
  }
}

// ---------------------------------------------------------------------------
// Chunked scan over fragment-blocked Cb.
// For (t, b4, h): one aligned 16B word holds z[r=0..3] then f[r=0..3]
// (r = b&3, b = b4*4+r) at u16 offset t*32768 + (h>>3)*256 + b4*64 + (h&7)*8.
// Pass 1: per (chunk, b4, h): 4-channel affine coeffs (A,B), h_start = 0.
// ---------------------------------------------------------------------------
__global__ __launch_bounds__(256) void k_scan1(const u16* __restrict__ Cb,
                                               float* __restrict__ Ap,
                                               float* __restrict__ Bp) {
  int i = blockIdx.x * 256 + threadIdx.x;  // 65536 = NCHUNK * 4 * 1024
  int h  = i & (C_HID - 1);
  int b4 = (i >> 10) & 3;
  int c  = i >> 12;
  const size_t lane_off = (size_t)(h >> 3) * 256 + b4 * 64 + (h & 7) * 8;
  float hh[4] = {0.f, 0.f, 0.f, 0.f}, P[4] = {1.f, 1.f, 1.f, 1.f};
#pragma unroll 8
  for (int tt = 0; tt < CLEN; ++tt) {
    size_t t = (size_t)c * CLEN + tt;
    uint4 v = *reinterpret_cast<const uint4*>(Cb + t * 32768 + lane_off);
    float z[4] = {bf2f(v.x & 0xffffu), bf2f(v.x >> 16),
                  bf2f(v.y & 0xffffu), bf2f(v.y >> 16)};
    float f[4] = {bf2f(v.z & 0xffffu), bf2f(v.z >> 16),
                  bf2f(v.w & 0xffffu), bf2f(v.w >> 16)};
#pragma unroll
    for (int r = 0; r < 4; ++r) {
      hh[r] += f[r] * (z[r] - hh[r]);
      P[r]  *= (1.f - f[r]);
    }
  }
  *reinterpret_cast<f32x4*>(Ap + (size_t)i * 4) = (f32x4){hh[0], hh[1], hh[2], hh[3]};
  *reinterpret_cast<f32x4*>(Bp + (size_t)i * 4) = (f32x4){P[0], P[1], P[2], P[3]};
}

// Pass 2: per (b4,h) combine the NCHUNK affine maps; emit per-chunk h_start.
__global__ __launch_bounds__(256) void k_scan2(const float* __restrict__ Ap,
                                               const float* __restrict__ Bp,
                                               float* __restrict__ St) {
  int j = blockIdx.x * 256 + threadIdx.x;  // 4096 = 4 * 1024
  float hh[4] = {0.f, 0.f, 0.f, 0.f};
#pragma unroll
  for (int c = 0; c < NCHUNK; ++c) {
    size_t idx = ((size_t)c * 4096 + j) * 4;
    *reinterpret_cast<f32x4*>(St + idx) = (f32x4){hh[0], hh[1], hh[2], hh[3]};
    f32x4 A = *reinterpret_cast<const f32x4*>(Ap + idx);
    f32x4 B = *reinterpret_cast<const f32x4*>(Bp + idx);
#pragma unroll
    for (int r = 0; r < 4; ++r) hh[r] = A[r] + B[r] * hh[r];
  }
}

// Pass 3: re-run each chunk from its correct start state, write H (+ tail).
__global__ __launch_bounds__(256) void k_scan3(const u16* __restrict__ Cb,
                                               const float* __restrict__ St,
                                               float* __restrict__ out) {
  int i = blockIdx.x * 256 + threadIdx.x;  // 65536
  int h  = i & (C_HID - 1);
  int b4 = (i >> 10) & 3;
  int c  = i >> 12;
  const size_t lane_off = (size_t)(h >> 3) * 256 + b4 * 64 + (h & 7) * 8;
  f32x4 s = *reinterpret_cast<const f32x4*>(St + (size_t)i * 4);
  float hh[4] = {s[0], s[1], s[2], s[3]};
#pragma unroll 8
  for (int tt = 0; tt < CLEN; ++tt) {
    size_t t = (size_t)c * CLEN + tt;
    uint4 v = *reinterpret_cast<const uint4*>(Cb + t * 32768 + lane_off);
    float z[4] = {bf2f(v.x & 0xffffu), bf2f(v.x >> 16),
                  bf2f(v.y & 0xffffu), bf2f(v.y >> 16)};
    float f[4] = {bf2f(v.z & 0xffffu), bf2f(v.z >> 16),
                  bf2f(v.w & 0xffffu), bf2f(v.w >> 16)};
    float* op = out + t * 16384 + (size_t)b4 * 4096 + h;
#pragma unroll
    for (int r = 0; r < 4; ++r) {
      hh[r] += f[r] * (z[r] - hh[r]);
      op[r * 1024] = hh[r];
    }
  }
  if (c == NCHUNK - 1) {
    float* tp = out + (size_t)M_ROWS * C_HID + (size_t)b4 * 4096 + h;
#pragma unroll
    for (int r = 0; r < 4; ++r) tp[r * 1024] = hh[r];  // H[-1]
  }
}

// ---------------------------------------------------------------------------
extern "C" void kernel_launch(void* const* d_in, const int* in_sizes, int n_in,
                              void* d_out, int out_size, void* d_ws, size_t ws_size,
                              hipStream_t stream) {
  const float* X   = (const float*)d_in[0];
  const float* Wz  = (const float*)d_in[1];
  const float* bz  = (const float*)d_in[2];
  const float* Wf  = (const float*)d_in[3];
  const float* bf_ = (const float*)d_in[4];
  float* out = (float*)d_out;

  // workspace layout (bf16 = u16):
  u16* Xp = (u16*)d_ws;                                 // (16384+16)*1024 u16
  u16* Wt = Xp + (size_t)(M_ROWS + B_SZ) * C_IN;        // 2048*2048 u16
  u16* Cb = Wt + (size_t)N_COLS * K_DIM;                // 16384*2048 u16 (blocked)
  // scan scratch reuses the (dead after GEMM) Xp region: 3 MB << 33 MB
  float* Ap = (float*)Xp;                               // 65536*4 f32 = 1 MB
  float* Bp = Ap + (size_t)NCHUNK * NBH;                // 1 MB
  float* St = Bp + (size_t)NCHUNK * NBH;                // 1 MB

  hipLaunchKernelGGL(k_convert_x, dim3(16400), dim3(256), 0, stream, X, Xp);
  hipLaunchKernelGGL(k_repack_w, dim3(8192), dim3(256), 0, stream, Wz, Wf, Wt);
  hipLaunchKernelGGL(k_gemm8, dim3((M_ROWS / 256) * (N_COLS / 256)), dim3(512), 0,
                     stream, Xp, Wt, bz, bf_, Cb);
  hipLaunchKernelGGL(k_scan1, dim3(256), dim3(256), 0, stream, Cb, Ap, Bp);
  hipLaunchKernelGGL(k_scan2, dim3(16), dim3(256), 0, stream, Ap, Bp, St);
  hipLaunchKernelGGL(k_scan3, dim3(256), dim3(256), 0, stream, Cb, St, out);
}